// Round 1
// baseline (165.974 us; speedup 1.0000x reference)
//
#include <hip/hip_runtime.h>

// Problem constants
#define NB   4096   // B
#define ND   256    // D
#define N2B  8192   // 2B
#define INV_T 2.0f  // 1/TEMP, TEMP=0.5

typedef __attribute__((ext_vector_type(8))) short bf16x8;
typedef __attribute__((ext_vector_type(4))) float f32x4;

__device__ __forceinline__ void gload_lds16(const void* g, void* l) {
  __builtin_amdgcn_global_load_lds(
      (const __attribute__((address_space(1))) void*)g,
      (__attribute__((address_space(3))) void*)l, 16, 0, 0);
}

// fp32 -> bf16 (RNE) as raw bits
__device__ __forceinline__ unsigned short f2b(float f) {
  unsigned int u = __float_as_uint(f);
  u = (u + 0x7fffu + ((u >> 16) & 1u)) >> 16;
  return (unsigned short)u;
}
__device__ __forceinline__ float b2f(unsigned short h) {
  return __uint_as_float(((unsigned int)h) << 16);
}

// Kernel A: L2-normalize rows of [x_i; x_j] -> Z (bf16 bits), and
// rowsum[r] = -exp(diag_r / T) where diag_r = sum(zb^2) (matches what the
// MFMA diagonal will compute up to accumulation order). Also zero lossAcc.
__global__ __launch_bounds__(256) void k_normalize(
    const float* __restrict__ xi, const float* __restrict__ xj,
    unsigned short* __restrict__ Z, float* __restrict__ rowsum,
    float* __restrict__ lossAcc) {
  if (blockIdx.x == 0 && threadIdx.x == 0) *lossAcc = 0.0f;
  int wave = threadIdx.x >> 6, lane = threadIdx.x & 63;
  int row = (int)blockIdx.x * 4 + wave;
  const float* src = (row < NB) ? (xi + (size_t)row * ND)
                                : (xj + (size_t)(row - NB) * ND);
  float4 v = *(const float4*)(src + lane * 4);
  float ss = v.x * v.x + v.y * v.y + v.z * v.z + v.w * v.w;
#pragma unroll
  for (int m = 1; m < 64; m <<= 1) ss += __shfl_xor(ss, m, 64);
  float scale = 1.0f / fmaxf(sqrtf(ss), 1e-12f);
  unsigned short h0 = f2b(v.x * scale), h1 = f2b(v.y * scale);
  unsigned short h2 = f2b(v.z * scale), h3 = f2b(v.w * scale);
  ushort4 st; st.x = h0; st.y = h1; st.z = h2; st.w = h3;
  *(ushort4*)(Z + (size_t)row * ND + lane * 4) = st;
  float f0 = b2f(h0), f1 = b2f(h1), f2 = b2f(h2), f3 = b2f(h3);
  float d = f0 * f0 + f1 * f1 + f2 * f2 + f3 * f3;
#pragma unroll
  for (int m = 1; m < 64; m <<= 1) d += __shfl_xor(d, m, 64);
  if (lane == 0) rowsum[row] = -__expf(d * INV_T);
}

// Kernel B: tiled Z*Z^T with fused exp()/row-sum. 128x128 tile, 4 waves,
// each wave 4x4 accs of mfma_f32_16x16x32_bf16. BK=64, global_load_lds
// width=16 staging, XOR-swizzled LDS (chunk ^ (row&7)) -> conflict-free
// ds_read_b128 with lane-linear staging.
#define BK 64
__global__ __launch_bounds__(256) void k_gemm_exp(
    const unsigned short* __restrict__ Z, float* __restrict__ rowsum) {
  __shared__ alignas(16) unsigned short As[128 * BK];
  __shared__ alignas(16) unsigned short Bs[128 * BK];

  int tid = threadIdx.x;
  int wave = tid >> 6, lane = tid & 63;
  int tileM = blockIdx.x, tileN = blockIdx.y;
  int warp_m = wave & 1, warp_n = wave >> 1;
  int quad = lane >> 4, c16 = lane & 15;

  f32x4 acc[4][4] = {};

  const unsigned short* Ag = Z + (size_t)tileM * 128 * ND;
  const unsigned short* Bg = Z + (size_t)tileN * 128 * ND;

  int lr = lane >> 3;   // row-in-call 0..7
  int cs = lane & 7;    // LDS chunk slot 0..7

  for (int s = 0; s < 4; ++s) {
    int k0 = s * BK;
    // stage A/B tiles: each wave stages 32 rows in 4 calls of 8 rows
#pragma unroll
    for (int call = 0; call < 4; ++call) {
      int r0 = wave * 32 + call * 8;      // wave-uniform LDS base row
      int row = r0 + lr;
      int gc = cs ^ (row & 7);            // fetch global chunk gc into slot cs
      int goff = row * ND + k0 + gc * 8;  // elements
      gload_lds16(Ag + goff, &As[r0 * BK]);
      gload_lds16(Bg + goff, &Bs[r0 * BK]);
    }
    asm volatile("s_waitcnt vmcnt(0)" ::: "memory");
    __syncthreads();

#pragma unroll
    for (int t = 0; t < 2; ++t) {
      bf16x8 af[4], bfr[4];
      int c = t * 4 + quad;  // chunk index within row (k = c*8..c*8+7)
#pragma unroll
      for (int mi = 0; mi < 4; ++mi) {
        int row = warp_m * 64 + mi * 16 + c16;
        af[mi] = *(const bf16x8*)&As[(row * 8 + (c ^ (row & 7))) * 8];
      }
#pragma unroll
      for (int ni = 0; ni < 4; ++ni) {
        int row = warp_n * 64 + ni * 16 + c16;
        bfr[ni] = *(const bf16x8*)&Bs[(row * 8 + (c ^ (row & 7))) * 8];
      }
#pragma unroll
      for (int mi = 0; mi < 4; ++mi)
#pragma unroll
        for (int ni = 0; ni < 4; ++ni)
          acc[mi][ni] = __builtin_amdgcn_mfma_f32_16x16x32_bf16(
              af[mi], bfr[ni], acc[mi][ni], 0, 0, 0);
    }
    __syncthreads();
  }

  // Epilogue: exp(sim/T) and row-sum. C/D layout: col=lane&15,
  // row=(lane>>4)*4+reg. Lane partials rs[mi][r]; reduce across the 16
  // lanes sharing a row (bits 0..3), then predicated atomics.
  float rs[4][4];
#pragma unroll
  for (int mi = 0; mi < 4; ++mi)
#pragma unroll
    for (int r = 0; r < 4; ++r) rs[mi][r] = 0.0f;
#pragma unroll
  for (int mi = 0; mi < 4; ++mi)
#pragma unroll
    for (int ni = 0; ni < 4; ++ni)
#pragma unroll
      for (int r = 0; r < 4; ++r)
        rs[mi][r] += __expf(acc[mi][ni][r] * INV_T);
#pragma unroll
  for (int m = 1; m <= 8; m <<= 1)
#pragma unroll
    for (int mi = 0; mi < 4; ++mi)
#pragma unroll
      for (int r = 0; r < 4; ++r)
        rs[mi][r] += __shfl_xor(rs[mi][r], m, 64);

  int rowbase = tileM * 128 + warp_m * 64;
#pragma unroll
  for (int mi = 0; mi < 4; ++mi)
#pragma unroll
    for (int r = 0; r < 4; ++r)
      if (c16 == mi * 4 + r)
        atomicAdd(&rowsum[rowbase + mi * 16 + quad * 4 + r], rs[mi][r]);
}

// Kernel C: per r<B, pos_r = dot(zb_r, zb_{r+B}); accumulate
// log(denom_r) + log(denom_{r+B}) - 2*pos_r/T into lossAcc.
__global__ __launch_bounds__(256) void k_finish(
    const unsigned short* __restrict__ Z, const float* __restrict__ rowsum,
    float* __restrict__ lossAcc) {
  int wave = threadIdx.x >> 6, lane = threadIdx.x & 63;
  int r = (int)blockIdx.x * 4 + wave;
  const unsigned short* zi = Z + (size_t)r * ND;
  const unsigned short* zj = Z + (size_t)(r + NB) * ND;
  ushort4 a = *(const ushort4*)(zi + lane * 4);
  ushort4 b = *(const ushort4*)(zj + lane * 4);
  float s = b2f(a.x) * b2f(b.x) + b2f(a.y) * b2f(b.y) +
            b2f(a.z) * b2f(b.z) + b2f(a.w) * b2f(b.w);
#pragma unroll
  for (int m = 1; m < 64; m <<= 1) s += __shfl_xor(s, m, 64);
  if (lane == 0) {
    float term = logf(rowsum[r]) + logf(rowsum[r + NB]) - 2.0f * INV_T * s;
    atomicAdd(lossAcc, term);
  }
}

__global__ void k_write(const float* __restrict__ lossAcc,
                        float* __restrict__ out) {
  out[0] = lossAcc[0] * (1.0f / (float)N2B);
}

extern "C" void kernel_launch(void* const* d_in, const int* in_sizes, int n_in,
                              void* d_out, int out_size, void* d_ws,
                              size_t ws_size, hipStream_t stream) {
  const float* xi = (const float*)d_in[0];
  const float* xj = (const float*)d_in[1];
  float* out = (float*)d_out;
  char* ws = (char*)d_ws;
  unsigned short* Z = (unsigned short*)ws;            // 8192*256*2 = 4 MiB
  float* rowsum = (float*)(ws + 4194304);             // 8192 floats
  float* lossAcc = (float*)(ws + 4194304 + 32768);    // 1 float

  k_normalize<<<dim3(2048), dim3(256), 0, stream>>>(xi, xj, Z, rowsum, lossAcc);
  k_gemm_exp<<<dim3(64, 64), dim3(256), 0, stream>>>(Z, rowsum);
  k_finish<<<dim3(1024), dim3(256), 0, stream>>>(Z, rowsum, lossAcc);
  k_write<<<dim3(1), dim3(1), 0, stream>>>(lossAcc, out);
}

// Round 2
// 111.986 us; speedup vs baseline: 1.4821x; 1.4821x over previous
//
#include <hip/hip_runtime.h>

// Problem constants
#define NB   4096   // B
#define ND   256    // D
#define N2B  8192   // 2B
#define INV_T 2.0f  // 1/TEMP, TEMP=0.5

typedef __attribute__((ext_vector_type(8))) short bf16x8;
typedef __attribute__((ext_vector_type(4))) float f32x4;

__device__ __forceinline__ void gload_lds16(const void* g, void* l) {
  __builtin_amdgcn_global_load_lds(
      (const __attribute__((address_space(1))) void*)g,
      (__attribute__((address_space(3))) void*)l, 16, 0, 0);
}

// fp32 -> bf16 (RNE) as raw bits
__device__ __forceinline__ unsigned short f2b(float f) {
  unsigned int u = __float_as_uint(f);
  u = (u + 0x7fffu + ((u >> 16) & 1u)) >> 16;
  return (unsigned short)u;
}
__device__ __forceinline__ float b2f(unsigned short h) {
  return __uint_as_float(((unsigned int)h) << 16);
}

// Kernel A: L2-normalize rows of [x_i; x_j] -> Z (bf16 bits). Block handles
// rows {r0, r0+1} of BOTH x_i and x_j (4 waves, one full row per wave:
// 64 lanes x float4 = 256 = D). Also:
//   rowsum[zrow] = -exp(diag/T)  (cancels the MFMA self-similarity term)
//   pos[r] = dot(z_i[r], z_j[r]) (via LDS exchange between i- and j-waves)
__global__ __launch_bounds__(256) void k_normalize(
    const float* __restrict__ xi, const float* __restrict__ xj,
    unsigned short* __restrict__ Z, float* __restrict__ rowsum,
    float* __restrict__ pos) {
  __shared__ float sh[2][256];
  int wave = threadIdx.x >> 6, lane = threadIdx.x & 63;
  int r = (int)blockIdx.x * 2 + (wave & 1);  // row in [0, NB)
  bool isJ = wave >= 2;
  const float* src = (isJ ? xj : xi) + (size_t)r * ND;
  int zrow = r + (isJ ? NB : 0);

  float4 v = *(const float4*)(src + lane * 4);
  float ss = v.x * v.x + v.y * v.y + v.z * v.z + v.w * v.w;
#pragma unroll
  for (int m = 1; m < 64; m <<= 1) ss += __shfl_xor(ss, m, 64);
  float scale = 1.0f / fmaxf(sqrtf(ss), 1e-12f);
  unsigned short h0 = f2b(v.x * scale), h1 = f2b(v.y * scale);
  unsigned short h2 = f2b(v.z * scale), h3 = f2b(v.w * scale);
  ushort4 st; st.x = h0; st.y = h1; st.z = h2; st.w = h3;
  *(ushort4*)(Z + (size_t)zrow * ND + lane * 4) = st;

  float f0 = b2f(h0), f1 = b2f(h1), f2 = b2f(h2), f3 = b2f(h3);
  float d = f0 * f0 + f1 * f1 + f2 * f2 + f3 * f3;
#pragma unroll
  for (int m = 1; m < 64; m <<= 1) d += __shfl_xor(d, m, 64);
  if (lane == 0) rowsum[zrow] = -__expf(d * INV_T);

  if (isJ) {
    float* s = sh[wave & 1] + lane * 4;
    s[0] = f0; s[1] = f1; s[2] = f2; s[3] = f3;
  }
  __syncthreads();
  if (!isJ) {
    const float* s = sh[wave] + lane * 4;
    float p = f0 * s[0] + f1 * s[1] + f2 * s[2] + f3 * s[3];
#pragma unroll
    for (int m = 1; m < 64; m <<= 1) p += __shfl_xor(p, m, 64);
    if (lane == 0) pos[r] = p;
  }
}

// Kernel B: lower-triangular tiled Z*Z^T with fused exp()/row+col sums.
// Only tiles tm >= tn are computed (2080 blocks). Off-diagonal tiles add
// exp row-sums to rowsum[tm-block] AND exp col-sums to rowsum[tn-block]
// (symmetry). 128x128 tile, 4 waves, 4x4 accs of mfma_f32_16x16x32_bf16,
// BK=64, global_load_lds width=16, XOR-swizzled LDS -> 0 bank conflicts.
#define BK 64
__global__ __launch_bounds__(256) void k_gemm_exp(
    const unsigned short* __restrict__ Z, float* __restrict__ rowsum) {
  __shared__ alignas(16) unsigned short As[128 * BK];
  __shared__ alignas(16) unsigned short Bs[128 * BK];

  int tid = threadIdx.x;
  int wave = tid >> 6, lane = tid & 63;

  // decode lower-triangular pair: tm >= tn
  int k = (int)blockIdx.x;
  int tm = (int)((sqrtf(8.0f * (float)k + 1.0f) - 1.0f) * 0.5f);
  while ((tm + 1) * (tm + 2) / 2 <= k) ++tm;
  while (tm * (tm + 1) / 2 > k) --tm;
  int tn = k - tm * (tm + 1) / 2;

  int warp_m = wave & 1, warp_n = wave >> 1;
  int quad = lane >> 4, c16 = lane & 15;

  f32x4 acc[4][4] = {};

  const unsigned short* Ag = Z + (size_t)tm * 128 * ND;
  const unsigned short* Bg = Z + (size_t)tn * 128 * ND;

  int lr = lane >> 3;   // row-in-call 0..7
  int cs = lane & 7;    // LDS chunk slot 0..7

  for (int s = 0; s < 4; ++s) {
    int k0 = s * BK;
#pragma unroll
    for (int call = 0; call < 4; ++call) {
      int r0 = wave * 32 + call * 8;      // wave-uniform LDS base row
      int row = r0 + lr;
      int gc = cs ^ (row & 7);            // fetch global chunk gc into slot cs
      int goff = row * ND + k0 + gc * 8;  // elements
      gload_lds16(Ag + goff, &As[r0 * BK]);
      gload_lds16(Bg + goff, &Bs[r0 * BK]);
    }
    asm volatile("s_waitcnt vmcnt(0)" ::: "memory");
    __syncthreads();

#pragma unroll
    for (int t = 0; t < 2; ++t) {
      bf16x8 af[4], bfr[4];
      int c = t * 4 + quad;  // chunk index within row
#pragma unroll
      for (int mi = 0; mi < 4; ++mi) {
        int row = warp_m * 64 + mi * 16 + c16;
        af[mi] = *(const bf16x8*)&As[(row * 8 + (c ^ (row & 7))) * 8];
      }
#pragma unroll
      for (int ni = 0; ni < 4; ++ni) {
        int row = warp_n * 64 + ni * 16 + c16;
        bfr[ni] = *(const bf16x8*)&Bs[(row * 8 + (c ^ (row & 7))) * 8];
      }
#pragma unroll
      for (int mi = 0; mi < 4; ++mi)
#pragma unroll
        for (int ni = 0; ni < 4; ++ni)
          acc[mi][ni] = __builtin_amdgcn_mfma_f32_16x16x32_bf16(
              af[mi], bfr[ni], acc[mi][ni], 0, 0, 0);
    }
    __syncthreads();
  }

  // Epilogue. C/D layout: col=lane&15, row=(lane>>4)*4+reg.
  // e = exp(sim/T); rs[mi][r] accumulates over ni (row partials);
  // cs4[ni] accumulates over mi,r (col partials, off-diag tiles only).
  bool off = (tm != tn);
  float rs[4][4];
  float cs4[4] = {0.f, 0.f, 0.f, 0.f};
#pragma unroll
  for (int mi = 0; mi < 4; ++mi)
#pragma unroll
    for (int r = 0; r < 4; ++r) rs[mi][r] = 0.0f;
#pragma unroll
  for (int mi = 0; mi < 4; ++mi)
#pragma unroll
    for (int ni = 0; ni < 4; ++ni)
#pragma unroll
      for (int r = 0; r < 4; ++r) {
        float e = __expf(acc[mi][ni][r] * INV_T);
        rs[mi][r] += e;
        cs4[ni] += e;
      }

  // row sums: reduce across c16 bits (masks 1,2,4,8)
#pragma unroll
  for (int m = 1; m <= 8; m <<= 1)
#pragma unroll
    for (int mi = 0; mi < 4; ++mi)
#pragma unroll
      for (int r = 0; r < 4; ++r)
        rs[mi][r] += __shfl_xor(rs[mi][r], m, 64);

  int rowbase = tm * 128 + warp_m * 64;
#pragma unroll
  for (int mi = 0; mi < 4; ++mi)
#pragma unroll
    for (int r = 0; r < 4; ++r)
      if (c16 == mi * 4 + r)
        atomicAdd(&rowsum[rowbase + mi * 16 + quad * 4 + r], rs[mi][r]);

  if (off) {
    // col sums: reduce across quad bits (masks 16,32)
#pragma unroll
    for (int m = 16; m <= 32; m <<= 1)
#pragma unroll
      for (int ni = 0; ni < 4; ++ni)
        cs4[ni] += __shfl_xor(cs4[ni], m, 64);
    if (quad == 0) {
      int colbase = tn * 128 + warp_n * 64;
#pragma unroll
      for (int ni = 0; ni < 4; ++ni)
        atomicAdd(&rowsum[colbase + ni * 16 + c16], cs4[ni]);
    }
  }
}

// Kernel C: single-block, atomic-free final reduction.
// loss = (1/2B) * sum_r [ log(rowsum[r]) - pos[r mod B]/T ]
__global__ __launch_bounds__(1024) void k_final(
    const float* __restrict__ rowsum, const float* __restrict__ pos,
    float* __restrict__ out) {
  __shared__ float red[16];
  int tid = threadIdx.x;
  int wave = tid >> 6, lane = tid & 63;
  float acc = 0.0f;
#pragma unroll
  for (int t = 0; t < N2B / 1024; ++t) {
    int r = tid + t * 1024;
    acc += __logf(rowsum[r]) - INV_T * pos[r & (NB - 1)];
  }
#pragma unroll
  for (int m = 1; m < 64; m <<= 1) acc += __shfl_xor(acc, m, 64);
  if (lane == 0) red[wave] = acc;
  __syncthreads();
  if (tid == 0) {
    float t = 0.0f;
#pragma unroll
    for (int w = 0; w < 16; ++w) t += red[w];
    out[0] = t * (1.0f / (float)N2B);
  }
}

extern "C" void kernel_launch(void* const* d_in, const int* in_sizes, int n_in,
                              void* d_out, int out_size, void* d_ws,
                              size_t ws_size, hipStream_t stream) {
  const float* xi = (const float*)d_in[0];
  const float* xj = (const float*)d_in[1];
  float* out = (float*)d_out;
  char* ws = (char*)d_ws;
  unsigned short* Z = (unsigned short*)ws;            // 8192*256*2 = 4 MiB
  float* rowsum = (float*)(ws + 4194304);             // 8192 floats
  float* pos = (float*)(ws + 4194304 + 32768);        // 4096 floats

  k_normalize<<<dim3(NB / 2), dim3(256), 0, stream>>>(xi, xj, Z, rowsum, pos);
  k_gemm_exp<<<dim3(64 * 65 / 2), dim3(256), 0, stream>>>(Z, rowsum);
  k_final<<<dim3(1), dim3(1024), 0, stream>>>(rowsum, pos, out);
}

// Round 3
// 103.333 us; speedup vs baseline: 1.6062x; 1.0837x over previous
//
#include <hip/hip_runtime.h>

// Problem constants
#define NB   4096   // B
#define ND   256    // D
#define N2B  8192   // 2B
#define INV_T 2.0f  // 1/TEMP, TEMP=0.5

typedef __attribute__((ext_vector_type(8))) short bf16x8;
typedef __attribute__((ext_vector_type(4))) float f32x4;

__device__ __forceinline__ void gload_lds16(const void* g, void* l) {
  __builtin_amdgcn_global_load_lds(
      (const __attribute__((address_space(1))) void*)g,
      (__attribute__((address_space(3))) void*)l, 16, 0, 0);
}

// fp32 -> bf16 (RNE) as raw bits
__device__ __forceinline__ unsigned short f2b(float f) {
  unsigned int u = __float_as_uint(f);
  u = (u + 0x7fffu + ((u >> 16) & 1u)) >> 16;
  return (unsigned short)u;
}
__device__ __forceinline__ float b2f(unsigned short h) {
  return __uint_as_float(((unsigned int)h) << 16);
}

// Kernel A: L2-normalize rows of [x_i; x_j] -> Z (bf16 bits). Block handles
// rows {r0, r0+1} of BOTH x_i and x_j (4 waves, one full row per wave).
//   diagE[zrow] = exp(diag/T)   (self-similarity term, subtracted in k_final)
//   pos[r] = dot(z_i[r], z_j[r]) (LDS exchange between i- and j-waves)
// Block 0 also zero-inits lossAcc and ticket (visible to later dispatches).
__global__ __launch_bounds__(256) void k_normalize(
    const float* __restrict__ xi, const float* __restrict__ xj,
    unsigned short* __restrict__ Z, float* __restrict__ diagE,
    float* __restrict__ pos, float* __restrict__ lossAcc,
    unsigned int* __restrict__ ticket) {
  __shared__ float sh[2][256];
  if (blockIdx.x == 0 && threadIdx.x == 0) { *lossAcc = 0.0f; *ticket = 0u; }
  int wave = threadIdx.x >> 6, lane = threadIdx.x & 63;
  int r = (int)blockIdx.x * 2 + (wave & 1);  // row in [0, NB)
  bool isJ = wave >= 2;
  const float* src = (isJ ? xj : xi) + (size_t)r * ND;
  int zrow = r + (isJ ? NB : 0);

  float4 v = *(const float4*)(src + lane * 4);
  float ss = v.x * v.x + v.y * v.y + v.z * v.z + v.w * v.w;
#pragma unroll
  for (int m = 1; m < 64; m <<= 1) ss += __shfl_xor(ss, m, 64);
  float scale = 1.0f / fmaxf(sqrtf(ss), 1e-12f);
  unsigned short h0 = f2b(v.x * scale), h1 = f2b(v.y * scale);
  unsigned short h2 = f2b(v.z * scale), h3 = f2b(v.w * scale);
  ushort4 st; st.x = h0; st.y = h1; st.z = h2; st.w = h3;
  *(ushort4*)(Z + (size_t)zrow * ND + lane * 4) = st;

  float f0 = b2f(h0), f1 = b2f(h1), f2 = b2f(h2), f3 = b2f(h3);
  float d = f0 * f0 + f1 * f1 + f2 * f2 + f3 * f3;
#pragma unroll
  for (int m = 1; m < 64; m <<= 1) d += __shfl_xor(d, m, 64);
  if (lane == 0) diagE[zrow] = __expf(d * INV_T);

  if (isJ) {
    float* s = sh[wave & 1] + lane * 4;
    s[0] = f0; s[1] = f1; s[2] = f2; s[3] = f3;
  }
  __syncthreads();
  if (!isJ) {
    const float* s = sh[wave] + lane * 4;
    float p = f0 * s[0] + f1 * s[1] + f2 * s[2] + f3 * s[3];
#pragma unroll
    for (int m = 1; m < 64; m <<= 1) p += __shfl_xor(p, m, 64);
    if (lane == 0) pos[r] = p;
  }
}

// Kernel B: lower-triangular tiled Z*Z^T, fused exp(), ATOMIC-FREE epilogue.
// Tile (tm,tn), tm>=tn. Partial-sum matrix R[8192][128]:
//   row-partials  (rows of tm-block, summed over this wave's 64 cols)
//     -> R[row][tn*2 + warp_n]
//   col-partials  (cols of tn-block, summed over this wave's 64 rows,
//                  off-diagonal tiles only, by symmetry)
//     -> R[col][tm*2 + warp_m]
// Slot-uniqueness: for row r in row-block a, slots s=b*2+h with b<a come from
// row-parts of tile (a,b); b==a from the diagonal tile's row-parts; b>a from
// col-parts of tile (b,a). Every slot written exactly once; plain stores.
#define BK 64
__global__ __launch_bounds__(256) void k_gemm_exp(
    const unsigned short* __restrict__ Z, float* __restrict__ R) {
  __shared__ alignas(16) unsigned short As[128 * BK];
  __shared__ alignas(16) unsigned short Bs[128 * BK];

  int tid = threadIdx.x;
  int wave = tid >> 6, lane = tid & 63;

  // decode lower-triangular pair: tm >= tn
  int k = (int)blockIdx.x;
  int tm = (int)((sqrtf(8.0f * (float)k + 1.0f) - 1.0f) * 0.5f);
  while ((tm + 1) * (tm + 2) / 2 <= k) ++tm;
  while (tm * (tm + 1) / 2 > k) --tm;
  int tn = k - tm * (tm + 1) / 2;

  int warp_m = wave & 1, warp_n = wave >> 1;
  int quad = lane >> 4, c16 = lane & 15;

  f32x4 acc[4][4] = {};

  const unsigned short* Ag = Z + (size_t)tm * 128 * ND;
  const unsigned short* Bg = Z + (size_t)tn * 128 * ND;

  int lr = lane >> 3;   // row-in-call 0..7
  int cs = lane & 7;    // LDS chunk slot 0..7

  for (int s = 0; s < 4; ++s) {
    int k0 = s * BK;
#pragma unroll
    for (int call = 0; call < 4; ++call) {
      int r0 = wave * 32 + call * 8;      // wave-uniform LDS base row
      int row = r0 + lr;
      int gc = cs ^ (row & 7);            // fetch global chunk gc into slot cs
      int goff = row * ND + k0 + gc * 8;  // elements
      gload_lds16(Ag + goff, &As[r0 * BK]);
      gload_lds16(Bg + goff, &Bs[r0 * BK]);
    }
    asm volatile("s_waitcnt vmcnt(0)" ::: "memory");
    __syncthreads();

#pragma unroll
    for (int t = 0; t < 2; ++t) {
      bf16x8 af[4], bfr[4];
      int c = t * 4 + quad;  // chunk index within row
#pragma unroll
      for (int mi = 0; mi < 4; ++mi) {
        int row = warp_m * 64 + mi * 16 + c16;
        af[mi] = *(const bf16x8*)&As[(row * 8 + (c ^ (row & 7))) * 8];
      }
#pragma unroll
      for (int ni = 0; ni < 4; ++ni) {
        int row = warp_n * 64 + ni * 16 + c16;
        bfr[ni] = *(const bf16x8*)&Bs[(row * 8 + (c ^ (row & 7))) * 8];
      }
#pragma unroll
      for (int mi = 0; mi < 4; ++mi)
#pragma unroll
        for (int ni = 0; ni < 4; ++ni)
          acc[mi][ni] = __builtin_amdgcn_mfma_f32_16x16x32_bf16(
              af[mi], bfr[ni], acc[mi][ni], 0, 0, 0);
    }
    __syncthreads();
  }

  // Epilogue. C/D layout: col=lane&15, row=(lane>>4)*4+reg.
  bool off = (tm != tn);
  float rs[4][4];
  float cs4[4] = {0.f, 0.f, 0.f, 0.f};
#pragma unroll
  for (int mi = 0; mi < 4; ++mi)
#pragma unroll
    for (int r = 0; r < 4; ++r) rs[mi][r] = 0.0f;
#pragma unroll
  for (int mi = 0; mi < 4; ++mi)
#pragma unroll
    for (int ni = 0; ni < 4; ++ni)
#pragma unroll
      for (int r = 0; r < 4; ++r) {
        float e = __expf(acc[mi][ni][r] * INV_T);
        rs[mi][r] += e;
        cs4[ni] += e;
      }

  // row-partials: reduce across c16 bits (masks 1,2,4,8)
#pragma unroll
  for (int m = 1; m <= 8; m <<= 1)
#pragma unroll
    for (int mi = 0; mi < 4; ++mi)
#pragma unroll
      for (int r = 0; r < 4; ++r)
        rs[mi][r] += __shfl_xor(rs[mi][r], m, 64);

  int rowbase = tm * 128 + warp_m * 64;
  int rslot = tn * 2 + warp_n;
#pragma unroll
  for (int mi = 0; mi < 4; ++mi)
#pragma unroll
    for (int r = 0; r < 4; ++r)
      if (c16 == mi * 4 + r)
        R[(size_t)(rowbase + mi * 16 + quad * 4 + r) * 128 + rslot] = rs[mi][r];

  if (off) {
    // col-partials: reduce across quad bits (masks 16,32)
#pragma unroll
    for (int m = 16; m <= 32; m <<= 1)
#pragma unroll
      for (int ni = 0; ni < 4; ++ni)
        cs4[ni] += __shfl_xor(cs4[ni], m, 64);
    if (quad == 0) {
      int colbase = tn * 128 + warp_n * 64;
      int cslot = tm * 2 + warp_m;
#pragma unroll
      for (int ni = 0; ni < 4; ++ni)
        R[(size_t)(colbase + ni * 16 + c16) * 128 + cslot] = cs4[ni];
    }
  }
}

// Kernel C: 128 blocks x 64 rows. rowsum[r] = sum_s R[r][s] - diagE[r];
// term = log(rowsum) - pos[r%B]/T. Block-reduce -> one atomicAdd per block;
// ticketed last block writes out = lossAcc / 2B.
__global__ __launch_bounds__(256) void k_final(
    const float* __restrict__ R, const float* __restrict__ diagE,
    const float* __restrict__ pos, float* __restrict__ lossAcc,
    unsigned int* __restrict__ ticket, float* __restrict__ out) {
  __shared__ float red[4];
  int tid = threadIdx.x;
  int wave = tid >> 6, lane = tid & 63;
  int row = (int)blockIdx.x * 64 + (tid >> 2);   // 4 threads per row
  int c0 = (tid & 3) * 32;

  const float* Rr = R + (size_t)row * 128 + c0;
  float s = 0.0f;
#pragma unroll
  for (int i = 0; i < 8; ++i) {
    float4 v = *(const float4*)(Rr + i * 4);
    s += v.x + v.y + v.z + v.w;
  }
  // reduce the 4 lanes of each row (masks 1,2): all 4 end with the row sum
  s += __shfl_xor(s, 1, 64);
  s += __shfl_xor(s, 2, 64);
  // every lane computes its row's term, scaled by 1/4 (4 redundant lanes)
  float term = (__logf(s - diagE[row]) - INV_T * pos[row & (NB - 1)]) * 0.25f;
#pragma unroll
  for (int m = 1; m < 64; m <<= 1) term += __shfl_xor(term, m, 64);
  if (lane == 0) red[wave] = term;
  __syncthreads();
  if (tid == 0) {
    float bs = red[0] + red[1] + red[2] + red[3];
    atomicAdd(lossAcc, bs);
    __threadfence();
    unsigned int old = atomicAdd(ticket, 1u);
    if (old == 127u) {
      float v = atomicAdd(lossAcc, 0.0f);  // atomic read after all adds
      out[0] = v * (1.0f / (float)N2B);
    }
  }
}

extern "C" void kernel_launch(void* const* d_in, const int* in_sizes, int n_in,
                              void* d_out, int out_size, void* d_ws,
                              size_t ws_size, hipStream_t stream) {
  const float* xi = (const float*)d_in[0];
  const float* xj = (const float*)d_in[1];
  float* out = (float*)d_out;
  char* ws = (char*)d_ws;
  unsigned short* Z = (unsigned short*)ws;           // 4 MiB
  float* R = (float*)(ws + (4u << 20));              // 8192*128*4 = 4 MiB
  float* pos = (float*)(ws + (8u << 20));            // 16 KiB
  float* diagE = (float*)(ws + (8u << 20) + 65536);  // 32 KiB
  float* lossAcc = (float*)(ws + (8u << 20) + 131072);
  unsigned int* ticket = (unsigned int*)(ws + (8u << 20) + 131072 + 64);

  k_normalize<<<dim3(NB / 2), dim3(256), 0, stream>>>(xi, xj, Z, diagE, pos,
                                                      lossAcc, ticket);
  k_gemm_exp<<<dim3(64 * 65 / 2), dim3(256), 0, stream>>>(Z, R);
  k_final<<<dim3(128), dim3(256), 0, stream>>>(R, diagE, pos, lossAcc, ticket,
                                               out);
}

// Round 4
// 100.182 us; speedup vs baseline: 1.6567x; 1.0315x over previous
//
#include <hip/hip_runtime.h>

// Problem constants
#define NB   4096   // B
#define ND   256    // D
#define N2B  8192   // 2B
#define INV_T 2.0f  // 1/TEMP, TEMP=0.5

typedef __attribute__((ext_vector_type(8))) short bf16x8;
typedef __attribute__((ext_vector_type(4))) float f32x4;

__device__ __forceinline__ void gload_lds16(const void* g, void* l) {
  __builtin_amdgcn_global_load_lds(
      (const __attribute__((address_space(1))) void*)g,
      (__attribute__((address_space(3))) void*)l, 16, 0, 0);
}

// fp32 -> bf16 (RNE) as raw bits
__device__ __forceinline__ unsigned short f2b(float f) {
  unsigned int u = __float_as_uint(f);
  u = (u + 0x7fffu + ((u >> 16) & 1u)) >> 16;
  return (unsigned short)u;
}
__device__ __forceinline__ float b2f(unsigned short h) {
  return __uint_as_float(((unsigned int)h) << 16);
}

// Kernel A: L2-normalize rows of [x_i; x_j] -> Z (bf16 bits).
//   diagE[zrow] = exp(diag/T)   (self term, subtracted in k_final)
//   pos[r] = dot(z_i[r], z_j[r]) (LDS exchange between i- and j-waves)
// Block 0 zero-inits lossAcc and ticket.
__global__ __launch_bounds__(256) void k_normalize(
    const float* __restrict__ xi, const float* __restrict__ xj,
    unsigned short* __restrict__ Z, float* __restrict__ diagE,
    float* __restrict__ pos, float* __restrict__ lossAcc,
    unsigned int* __restrict__ ticket) {
  __shared__ float sh[2][256];
  if (blockIdx.x == 0 && threadIdx.x == 0) { *lossAcc = 0.0f; *ticket = 0u; }
  int wave = threadIdx.x >> 6, lane = threadIdx.x & 63;
  int r = (int)blockIdx.x * 2 + (wave & 1);  // row in [0, NB)
  bool isJ = wave >= 2;
  const float* src = (isJ ? xj : xi) + (size_t)r * ND;
  int zrow = r + (isJ ? NB : 0);

  float4 v = *(const float4*)(src + lane * 4);
  float ss = v.x * v.x + v.y * v.y + v.z * v.z + v.w * v.w;
#pragma unroll
  for (int m = 1; m < 64; m <<= 1) ss += __shfl_xor(ss, m, 64);
  float scale = 1.0f / fmaxf(sqrtf(ss), 1e-12f);
  unsigned short h0 = f2b(v.x * scale), h1 = f2b(v.y * scale);
  unsigned short h2 = f2b(v.z * scale), h3 = f2b(v.w * scale);
  ushort4 st; st.x = h0; st.y = h1; st.z = h2; st.w = h3;
  *(ushort4*)(Z + (size_t)zrow * ND + lane * 4) = st;

  float f0 = b2f(h0), f1 = b2f(h1), f2 = b2f(h2), f3 = b2f(h3);
  float d = f0 * f0 + f1 * f1 + f2 * f2 + f3 * f3;
#pragma unroll
  for (int m = 1; m < 64; m <<= 1) d += __shfl_xor(d, m, 64);
  if (lane == 0) diagE[zrow] = __expf(d * INV_T);

  if (isJ) {
    float* s = sh[wave & 1] + lane * 4;
    s[0] = f0; s[1] = f1; s[2] = f2; s[3] = f3;
  }
  __syncthreads();
  if (!isJ) {
    const float* s = sh[wave] + lane * 4;
    float p = f0 * s[0] + f1 * s[1] + f2 * s[2] + f3 * s[3];
#pragma unroll
    for (int m = 1; m < 64; m <<= 1) p += __shfl_xor(p, m, 64);
    if (lane == 0) pos[r] = p;
  }
}

// Kernel B: A-stationary band GEMM + fused exp/rowsum.
// Grid 512 = 64 row-bands (128 rows) x 8 col-spans (1024 cols).
// Each wave holds its 32 A-rows (full K=256) in registers for the whole
// kernel; only B streams through LDS in 64-col tiles (32 KB, XOR-swizzled,
// conflict-free). Per tile per wave: 64 MFMA vs 8 staging loads.
// Rowsum partials complete in-block -> R[row][8], plain stores, no atomics.
#define CT 64  // cols per tile
__global__ __launch_bounds__(256) void k_gemm_exp(
    const unsigned short* __restrict__ Z, float* __restrict__ R) {
  __shared__ alignas(16) unsigned short Bs[CT * ND];  // 32 KiB

  int tid = threadIdx.x;
  int wave = tid >> 6, lane = tid & 63;
  int band = (int)blockIdx.x >> 3;   // 0..63
  int colq = (int)blockIdx.x & 7;    // 0..7
  int quad = lane >> 4, c16 = lane & 15;

  // A fragments in registers: wave owns rows band*128 + wave*32 .. +31
  // (2 row-groups of 16). Frag layout A[m=c16][k=kk*32+quad*8+j].
  bf16x8 afr[2][8];
  int rowA = band * 128 + wave * 32;
#pragma unroll
  for (int rg = 0; rg < 2; ++rg)
#pragma unroll
    for (int kk = 0; kk < 8; ++kk)
      afr[rg][kk] = *(const bf16x8*)(Z + (size_t)(rowA + rg * 16 + c16) * ND +
                                     kk * 32 + quad * 8);

  float rs[2][4];
#pragma unroll
  for (int rg = 0; rg < 2; ++rg)
#pragma unroll
    for (int r = 0; r < 4; ++r) rs[rg][r] = 0.0f;

  int lr1 = lane >> 5;  // row within staging call (0/1)
  int cs = lane & 31;   // LDS chunk slot 0..31

  for (int ct = 0; ct < 16; ++ct) {
    int colbase = colq * 1024 + ct * CT;  // global Z row of this tile's col 0
    __syncthreads();  // LDS reuse guard
#pragma unroll
    for (int j = 0; j < 8; ++j) {
      int r0 = wave * 16 + j * 2;         // wave-uniform LDS base row
      int row = r0 + lr1;
      int gc = cs ^ (row & 31);           // fetch global chunk gc into slot cs
      gload_lds16(Z + (size_t)(colbase + row) * ND + gc * 8, &Bs[r0 * ND]);
    }
    asm volatile("s_waitcnt vmcnt(0)" ::: "memory");
    __syncthreads();

    f32x4 acc[2][4] = {};
#pragma unroll
    for (int kk = 0; kk < 8; ++kk) {
      bf16x8 bfr[4];
#pragma unroll
      for (int ni = 0; ni < 4; ++ni) {
        int row = ni * 16 + c16;
        int slot = (kk * 4 + quad) ^ (row & 31);
        bfr[ni] = *(const bf16x8*)&Bs[row * ND + slot * 8];
      }
#pragma unroll
      for (int rg = 0; rg < 2; ++rg)
#pragma unroll
        for (int ni = 0; ni < 4; ++ni)
          acc[rg][ni] = __builtin_amdgcn_mfma_f32_16x16x32_bf16(
              afr[rg][kk], bfr[ni], acc[rg][ni], 0, 0, 0);
    }

    // fused exp + row-partial accumulate (C/D: col=c16, row=quad*4+reg)
#pragma unroll
    for (int rg = 0; rg < 2; ++rg)
#pragma unroll
      for (int ni = 0; ni < 4; ++ni)
#pragma unroll
        for (int r = 0; r < 4; ++r)
          rs[rg][r] += __expf(acc[rg][ni][r] * INV_T);
  }

  // reduce row-partials across the 16 cols held per lane group (c16 bits)
#pragma unroll
  for (int m = 1; m <= 8; m <<= 1)
#pragma unroll
    for (int rg = 0; rg < 2; ++rg)
#pragma unroll
      for (int r = 0; r < 4; ++r)
        rs[rg][r] += __shfl_xor(rs[rg][r], m, 64);

#pragma unroll
  for (int rg = 0; rg < 2; ++rg)
#pragma unroll
    for (int r = 0; r < 4; ++r)
      if (c16 == rg * 4 + r) {
        int row = rowA + rg * 16 + quad * 4 + r;
        R[(size_t)row * 8 + colq] = rs[rg][r];
      }
}

// Kernel C: 32 blocks x 256 rows. rowsum[r] = sum_{q<8} R[r][q] - diagE[r];
// term = log(rowsum) - pos[r%B]/T. Block-reduce -> one atomicAdd per block;
// ticketed last block writes out = lossAcc / 2B.
__global__ __launch_bounds__(256) void k_final(
    const float* __restrict__ R, const float* __restrict__ diagE,
    const float* __restrict__ pos, float* __restrict__ lossAcc,
    unsigned int* __restrict__ ticket, float* __restrict__ out) {
  __shared__ float red[4];
  int tid = threadIdx.x;
  int wave = tid >> 6, lane = tid & 63;
  int row = (int)blockIdx.x * 256 + tid;

  const float* Rr = R + (size_t)row * 8;
  float4 a = *(const float4*)(Rr);
  float4 b = *(const float4*)(Rr + 4);
  float s = (a.x + a.y + a.z + a.w) + (b.x + b.y + b.z + b.w) - diagE[row];
  float term = __logf(s) - INV_T * pos[row & (NB - 1)];
#pragma unroll
  for (int m = 1; m < 64; m <<= 1) term += __shfl_xor(term, m, 64);
  if (lane == 0) red[wave] = term;
  __syncthreads();
  if (tid == 0) {
    float bs = red[0] + red[1] + red[2] + red[3];
    atomicAdd(lossAcc, bs);
    __threadfence();
    unsigned int old = atomicAdd(ticket, 1u);
    if (old == 31u) {
      float v = atomicAdd(lossAcc, 0.0f);  // atomic read after all adds
      out[0] = v * (1.0f / (float)N2B);
    }
  }
}

extern "C" void kernel_launch(void* const* d_in, const int* in_sizes, int n_in,
                              void* d_out, int out_size, void* d_ws,
                              size_t ws_size, hipStream_t stream) {
  const float* xi = (const float*)d_in[0];
  const float* xj = (const float*)d_in[1];
  float* out = (float*)d_out;
  char* ws = (char*)d_ws;
  unsigned short* Z = (unsigned short*)ws;           // 4 MiB
  float* R = (float*)(ws + (4u << 20));              // 8192*8*4 = 256 KiB
  float* pos = (float*)(ws + (8u << 20));            // 16 KiB
  float* diagE = (float*)(ws + (8u << 20) + 65536);  // 32 KiB
  float* lossAcc = (float*)(ws + (8u << 20) + 131072);
  unsigned int* ticket = (unsigned int*)(ws + (8u << 20) + 131072 + 64);

  k_normalize<<<dim3(NB / 2), dim3(256), 0, stream>>>(xi, xj, Z, diagE, pos,
                                                      lossAcc, ticket);
  k_gemm_exp<<<dim3(512), dim3(256), 0, stream>>>(Z, R);
  k_final<<<dim3(32), dim3(256), 0, stream>>>(R, diagE, pos, lossAcc, ticket,
                                              out);
}